// Round 9
// baseline (222.582 us; speedup 1.0000x reference)
//
#include <hip/hip_runtime.h>
#include <stdint.h>

// B=8, C=256, N=2048. Pipeline (reassociated: x3@(x1^T x2) == (x3@x1^T)@x2):
//   prep:  Wcatb=bf16([W1;W2;W3]), W4cat=bf16([W4|W4]), featT=bf16(feat^T)
//   ybf   = Wcat@feat RAW bf16 + row partials   [8,1536,2048]
//   stats = reduce(partials) -> (mu, rsqrt)     [12288]
//   x2T   = normlrelu(x2)^T                     [8,2048,512]
//   Amb   = nl(x3) @ nl(x1)^T  (norm fused into reg-staging)  [8,512,512]
//   x4Ts  = split(nl(x1) - Am@x2n)^T  (norm fused into D-read epilogue)
//   z     = [W4|W4] @ x4Ts (fp32)               [8,256,2048]  (aliases ybf tail)
//   out   = lrelu(inorm(z))
// r5 lesson: >=2 blocks/CU beats fusion-into-load-path (coop 1/CU lost 60us).
// r8 lesson: 2-phase dbuf = -14us. r9: eliminate x1n3 intermediate (66MB);
// Am normalizes during reg-staging (T14 early-issue), x4 normalizes D in
// epilogue (both forms correctness-proven in r5).

#define LRELU_SLOPE 0.2f
#define EPS_IN 1e-5f

typedef __attribute__((ext_vector_type(8))) short short8v;  // 8 bf16 (4 VGPR)
typedef __attribute__((ext_vector_type(4))) float f32x4;

__device__ __forceinline__ unsigned short f2bf(float f) {
    unsigned int u = __builtin_bit_cast(unsigned int, f);
    u = (u + 0x7fffu + ((u >> 16) & 1u)) >> 16;  // RNE
    return (unsigned short)u;
}
__device__ __forceinline__ float bf2f(unsigned short h) {
    return __builtin_bit_cast(float, (unsigned int)h << 16);
}

typedef const __attribute__((address_space(1))) unsigned int* as1_uint_ptr;
typedef __attribute__((address_space(3))) unsigned int* as3_uint_ptr;

#define GLL16(g, l) __builtin_amdgcn_global_load_lds( \
    (as1_uint_ptr)(const void*)(g), (as3_uint_ptr)(void*)(l), 16, 0, 0)

enum { EP_F32 = 0, EP_BF16_STATS = 1, EP_SUB_T_SPLIT_NORM = 2 };

// normalize + lrelu 8 bf16 packed in uint4 -> uint4 (bf16 RNE out)
__device__ __forceinline__ uint4 norm8(uint4 v, float2 st)
{
    const unsigned int wd[4] = {v.x, v.y, v.z, v.w};
    unsigned int o[4];
#pragma unroll
    for (int i = 0; i < 4; ++i) {
        float a = __builtin_bit_cast(float, wd[i] << 16);
        float b = __builtin_bit_cast(float, wd[i] & 0xffff0000u);
        a = (a - st.x) * st.y; a = a >= 0.f ? a : LRELU_SLOPE * a;
        b = (b - st.x) * st.y; b = b >= 0.f ? b : LRELU_SLOPE * b;
        o[i] = (unsigned int)f2bf(a) | ((unsigned int)f2bf(b) << 16);
    }
    return make_uint4(o[0], o[1], o[2], o[3]);
}

// ---------------------------------------------------------------------------
// TN bf16 MFMA GEMM, 2-phase double-buffered (r8 structure). A:[M][K], B:[N][K]
// both k-major. BK=32, 4 waves (2x2). Grid: (N/BN, M/BM, bz).
// EP_F32: C fp32 [M][N].
// EP_BF16_STATS: C bf16 raw + per-row (sum,sumsq) partials.
// EP_SUB_T_SPLIT_NORM: dv = lrelu((bf2f(D[m][n])-mu[m])*rs[m]); s = dv - acc;
//   C bf16 [N][ldc]: hi at [n][m], lo = bf16(s-hi) at [n][m+ldc/2].
// ---------------------------------------------------------------------------
template<int BM, int BN, int EP>
__global__ __launch_bounds__(256)
void gemm_tn(const unsigned short* __restrict__ A, const unsigned short* __restrict__ B,
             const unsigned short* __restrict__ Dm, void* __restrict__ Cv,
             const float2* __restrict__ stats, float2* __restrict__ part,
             int K, int lda, int ldb, int ldd, int ldc,
             int64_t sA, int64_t sB, int64_t sD, int64_t sC)
{
    constexpr int FM = BM / 32, FN = BN / 32;
    const int bz = blockIdx.z;
    A += sA * bz;
    B += sB * bz;

    const int i0 = blockIdx.y * BM;
    const int j0 = blockIdx.x * BN;

    __shared__ __align__(16) unsigned short As[2][BM * 32];
    __shared__ __align__(16) unsigned short Bs[2][BN * 32];

    const int t = threadIdx.x;
    const int w = t >> 6, l = t & 63;
    const int wr = w >> 1, wc = w & 1;
    const int srow = l >> 2, skq = (l & 3) * 8;

    f32x4 acc[FM][FN];
#pragma unroll
    for (int fm = 0; fm < FM; ++fm)
#pragma unroll
        for (int fn = 0; fn < FN; ++fn)
            acc[fm][fn] = (f32x4){0.f, 0.f, 0.f, 0.f};

    const int NT = K / 32;

    // prologue: stage tile 0 into buffer 0
#pragma unroll
    for (int q = 0; q < BM / 64; ++q) {
        const int seg = w * (BM / 64) + q;
        GLL16(A + (size_t)(i0 + seg * 16 + srow) * lda + skq, &As[0][seg * 512]);
    }
#pragma unroll
    for (int q = 0; q < BN / 64; ++q) {
        const int seg = w * (BN / 64) + q;
        GLL16(B + (size_t)(j0 + seg * 16 + srow) * ldb + skq, &Bs[0][seg * 512]);
    }
    __syncthreads();  // drains vmcnt: tile 0 resident

    for (int tt = 0; tt < NT; ++tt) {
        const int cur = tt & 1;
        if (tt + 1 < NT) {  // stage next tile (flies during compute)
            const int k0 = (tt + 1) * 32;
#pragma unroll
            for (int q = 0; q < BM / 64; ++q) {
                const int seg = w * (BM / 64) + q;
                GLL16(A + (size_t)(i0 + seg * 16 + srow) * lda + k0 + skq, &As[cur ^ 1][seg * 512]);
            }
#pragma unroll
            for (int q = 0; q < BN / 64; ++q) {
                const int seg = w * (BN / 64) + q;
                GLL16(B + (size_t)(j0 + seg * 16 + srow) * ldb + k0 + skq, &Bs[cur ^ 1][seg * 512]);
            }
        }
        short8v a[FM], b[FN];
#pragma unroll
        for (int fm = 0; fm < FM; ++fm)
            a[fm] = *(const short8v*)&As[cur][(wr * (BM / 2) + fm * 16 + (l & 15)) * 32 + (l >> 4) * 8];
#pragma unroll
        for (int fn = 0; fn < FN; ++fn)
            b[fn] = *(const short8v*)&Bs[cur][(wc * (BN / 2) + fn * 16 + (l & 15)) * 32 + (l >> 4) * 8];
#pragma unroll
        for (int fm = 0; fm < FM; ++fm)
#pragma unroll
            for (int fn = 0; fn < FN; ++fn)
                acc[fm][fn] = __builtin_amdgcn_mfma_f32_16x16x32_bf16(a[fm], b[fn], acc[fm][fn], 0, 0, 0);
        __syncthreads();  // next-tile GLLs done + reads of cur done
    }

    // C/D frag: col = lane&15, row = (lane>>4)*4 + reg.
    const int cr4 = (l >> 4) * 4;
    const int cc = l & 15;

    if constexpr (EP == EP_F32) {
        float* C = (float*)Cv + sC * bz;
#pragma unroll
        for (int fm = 0; fm < FM; ++fm)
#pragma unroll
            for (int fn = 0; fn < FN; ++fn)
#pragma unroll
                for (int r = 0; r < 4; ++r)
                    C[(size_t)(i0 + wr * (BM / 2) + fm * 16 + cr4 + r) * ldc +
                      (j0 + wc * (BN / 2) + fn * 16 + cc)] = acc[fm][fn][r];
    } else if constexpr (EP == EP_SUB_T_SPLIT_NORM) {
        const unsigned short* D = Dm + sD * bz;
        unsigned short* C = (unsigned short*)Cv + sC * bz;
#pragma unroll
        for (int fm = 0; fm < FM; ++fm) {
            const int grow0 = i0 + wr * (BM / 2) + fm * 16 + cr4;
            float2 st[4];
#pragma unroll
            for (int r = 0; r < 4; ++r) st[r] = stats[bz * 1536 + grow0 + r];
#pragma unroll
            for (int fn = 0; fn < FN; ++fn) {
                const int gcol = j0 + wc * (BN / 2) + fn * 16 + cc;
                ushort4 hi4, lo4;
#pragma unroll
                for (int r = 0; r < 4; ++r) {
                    float dv = (bf2f(D[(size_t)(grow0 + r) * ldd + gcol]) - st[r].x) * st[r].y;
                    dv = dv >= 0.f ? dv : LRELU_SLOPE * dv;
                    const float sv = dv - acc[fm][fn][r];
                    const unsigned short h = f2bf(sv);
                    ((unsigned short*)&hi4)[r] = h;
                    ((unsigned short*)&lo4)[r] = f2bf(sv - bf2f(h));
                }
                *(ushort4*)&C[(size_t)gcol * ldc + grow0] = hi4;
                *(ushort4*)&C[(size_t)gcol * ldc + (ldc >> 1) + grow0] = lo4;
            }
        }
    } else {  // EP_BF16_STATS
        unsigned short* C = (unsigned short*)Cv + sC * bz;
        __shared__ float2 wp[2][BM];
#pragma unroll
        for (int fm = 0; fm < FM; ++fm) {
#pragma unroll
            for (int r = 0; r < 4; ++r) {
                float s = 0.f, q = 0.f;
#pragma unroll
                for (int fn = 0; fn < FN; ++fn) {
                    const float v = acc[fm][fn][r];
                    s += v; q += v * v;
                    C[(size_t)(i0 + wr * (BM / 2) + fm * 16 + cr4 + r) * ldc +
                      (j0 + wc * (BN / 2) + fn * 16 + cc)] = f2bf(v);
                }
#pragma unroll
                for (int m = 1; m < 16; m <<= 1) {
                    s += __shfl_xor(s, m, 64);
                    q += __shfl_xor(q, m, 64);
                }
                if ((l & 15) == 0)
                    wp[wc][wr * (BM / 2) + fm * 16 + cr4 + r] = make_float2(s, q);
            }
        }
        __syncthreads();
        if (t < BM) {
            const float2 p0 = wp[0][t], p1 = wp[1][t];
            part[(size_t)(bz * 1536 + i0 + t) * gridDim.x + blockIdx.x] =
                make_float2(p0.x + p1.x, p0.y + p1.y);
        }
    }
}

// ---------------------------------------------------------------------------
// Am = nl(x3) @ nl(x1)^T, norm fused into reg-staging. 64x64 tile, BK=32,
// K=2048. Reads RAW ybf rows + stats; T14 early-issue: loads for tile t+1
// fly during MFMA of tile t. Grid (8, 8, 8) = 512 blocks (2/CU).
// ---------------------------------------------------------------------------
__global__ __launch_bounds__(256)
void gemm_am(const unsigned short* __restrict__ ybf, const float2* __restrict__ stats,
             unsigned short* __restrict__ Amb)
{
    const int bz = blockIdx.z;
    const unsigned short* Yb = ybf + (size_t)bz * 3145728;
    const int i0 = blockIdx.y * 64;  // x3 row-tile
    const int j0 = blockIdx.x * 64;  // x1 row-tile

    __shared__ __align__(16) unsigned short As[64 * 32];
    __shared__ __align__(16) unsigned short Bs[64 * 32];

    const int t = threadIdx.x, w = t >> 6, l = t & 63;
    const int wr = w >> 1, wc = w & 1;
    const int srow = t >> 2;         // 0..63: staged row
    const int skq = (t & 3) * 8;     // k-offset (8 bf16 = 16B per thread)

    const float2 stA = stats[bz * 1536 + 1024 + i0 + srow];  // x3 row stats
    const float2 stB = stats[bz * 1536 + j0 + srow];         // x1 row stats
    const unsigned short* gA = Yb + (size_t)(1024 + i0 + srow) * 2048 + skq;
    const unsigned short* gB = Yb + (size_t)(j0 + srow) * 2048 + skq;

    f32x4 acc[2][2];
#pragma unroll
    for (int fm = 0; fm < 2; ++fm)
#pragma unroll
        for (int fn = 0; fn < 2; ++fn)
            acc[fm][fn] = (f32x4){0.f, 0.f, 0.f, 0.f};

    uint4 vA = *(const uint4*)gA;   // tile 0
    uint4 vB = *(const uint4*)gB;

    for (int tt = 0; tt < 64; ++tt) {
        if (tt) __syncthreads();     // prior tile's frag reads done
        *(uint4*)&As[srow * 32 + skq] = norm8(vA, stA);
        *(uint4*)&Bs[srow * 32 + skq] = norm8(vB, stB);
        if (tt + 1 < 64) {           // early-issue next tile: flies during MFMA
            vA = *(const uint4*)(gA + (size_t)(tt + 1) * 32);
            vB = *(const uint4*)(gB + (size_t)(tt + 1) * 32);
        }
        __syncthreads();

        short8v a[2], b[2];
#pragma unroll
        for (int fm = 0; fm < 2; ++fm)
            a[fm] = *(const short8v*)&As[(wr * 32 + fm * 16 + (l & 15)) * 32 + (l >> 4) * 8];
#pragma unroll
        for (int fn = 0; fn < 2; ++fn)
            b[fn] = *(const short8v*)&Bs[(wc * 32 + fn * 16 + (l & 15)) * 32 + (l >> 4) * 8];
#pragma unroll
        for (int fm = 0; fm < 2; ++fm)
#pragma unroll
            for (int fn = 0; fn < 2; ++fn)
                acc[fm][fn] = __builtin_amdgcn_mfma_f32_16x16x32_bf16(a[fm], b[fn], acc[fm][fn], 0, 0, 0);
    }

    unsigned short* C = Amb + (size_t)bz * 262144;
    const int cr4 = (l >> 4) * 4, cc = l & 15;
#pragma unroll
    for (int fm = 0; fm < 2; ++fm)
#pragma unroll
        for (int fn = 0; fn < 2; ++fn)
#pragma unroll
            for (int r = 0; r < 4; ++r)
                C[(size_t)(i0 + wr * 32 + fm * 16 + cr4 + r) * 512 +
                  (j0 + wc * 32 + fn * 16 + cc)] = f2bf(acc[fm][fn][r]);
}

// ---------------------------------------------------------------------------
// reduce partials -> (mu, rsqrt(var+eps)) per row. 12288 rows x 16 jtiles.
// ---------------------------------------------------------------------------
__global__ __launch_bounds__(256)
void reduce_stats(const float2* __restrict__ part, float2* __restrict__ stats)
{
    const int row = blockIdx.x * 256 + threadIdx.x;
    float S = 0.f, Q = 0.f;
#pragma unroll
    for (int j = 0; j < 16; ++j) {
        const float2 p = part[(size_t)row * 16 + j];
        S += p.x; Q += p.y;
    }
    const float mu = S * (1.0f / 2048.0f);
    const float var = Q * (1.0f / 2048.0f) - mu * mu;
    stats[row] = make_float2(mu, rsqrtf(var + EPS_IN));
}

// ---------------------------------------------------------------------------
// x2T = normlrelu(x2)^T, bf16. Reads raw ybf rows 512..1023. Grid (32,8,8).
// ---------------------------------------------------------------------------
__global__ __launch_bounds__(256)
void transpose_norm_x2(const unsigned short* __restrict__ ybf,
                       const float2* __restrict__ stats,
                       unsigned short* __restrict__ x2T)
{
    __shared__ __align__(16) unsigned short tile[64][68];
    const int t = threadIdx.x, bz = blockIdx.z;
    const unsigned short* in = ybf + (size_t)bz * 3145728 + (size_t)512 * 2048;
    unsigned short* outp = x2T + (size_t)bz * 1048576;
    const int r0 = blockIdx.y * 64, c0 = blockIdx.x * 64;
    const int ir = t >> 4, ic = (t & 15) * 4;

#pragma unroll
    for (int q = 0; q < 4; ++q) {
        const int rr = q * 16 + ir;
        const float2 st = stats[bz * 1536 + 512 + r0 + rr];
        const ushort4 v = *(const ushort4*)&in[(size_t)(r0 + rr) * 2048 + c0 + ic];
        const unsigned short vv[4] = {v.x, v.y, v.z, v.w};
#pragma unroll
        for (int j = 0; j < 4; ++j) {
            float e = (bf2f(vv[j]) - st.x) * st.y;
            e = e >= 0.f ? e : LRELU_SLOPE * e;
            tile[rr][ic + j] = f2bf(e);
        }
    }
    __syncthreads();

    const int n = t & 63, kc = (t >> 6) * 16;
    unsigned short* op = outp + (size_t)(c0 + n) * 512 + r0 + kc;
    unsigned int wo[8];
#pragma unroll
    for (int i = 0; i < 8; ++i)
        wo[i] = (unsigned int)tile[kc + 2 * i][n] | ((unsigned int)tile[kc + 2 * i + 1][n] << 16);
    *(uint4*)op       = make_uint4(wo[0], wo[1], wo[2], wo[3]);
    *(uint4*)(op + 8) = make_uint4(wo[4], wo[5], wo[6], wo[7]);
}

// ---------------------------------------------------------------------------
// Merged prep: blocks [0,512) cast weights; blocks [512,1536) feat^T->bf16.
// ---------------------------------------------------------------------------
__global__ __launch_bounds__(256)
void prep(const float* __restrict__ W1, const float* __restrict__ W2,
          const float* __restrict__ W3, const float* __restrict__ W4,
          unsigned short* __restrict__ Wcatb, unsigned short* __restrict__ W4cat,
          const float* __restrict__ feat, unsigned short* __restrict__ featT)
{
    const int b = blockIdx.x;
    const int t = threadIdx.x;
    if (b < 512) {
        const int wsel = b >> 7;
        const int local = ((b & 127) * 256 + t) * 4;
        const float* src = (wsel == 0) ? W1 : (wsel == 1) ? W2 : (wsel == 2) ? W3 : W4;
        const float4 v = *(const float4*)(src + local);
        const ushort4 pk = make_ushort4(f2bf(v.x), f2bf(v.y), f2bf(v.z), f2bf(v.w));
        if (wsel < 3) {
            *(ushort4*)(Wcatb + (size_t)wsel * 131072 + local) = pk;
        } else {
            const int o = local >> 9, c = local & 511;
            *(ushort4*)(W4cat + (size_t)o * 1024 + c)       = pk;
            *(ushort4*)(W4cat + (size_t)o * 1024 + 512 + c) = pk;
        }
    } else {
        __shared__ __align__(16) unsigned short tile[64][68];
        const int r = b - 512;
        const int bx = r & 31, by = (r >> 5) & 3, bz = r >> 7;
        const float* ip0 = feat + (size_t)bz * 524288;
        unsigned short* outp = featT + (size_t)bz * 524288;
        const int r0 = by * 64, c0 = bx * 64;
        const int ir = t >> 4, ic = (t & 15) * 4;
#pragma unroll
        for (int q = 0; q < 4; ++q) {
            const int rr = q * 16 + ir;
            const float4 v = *(const float4*)&ip0[(size_t)(r0 + rr) * 2048 + c0 + ic];
            tile[rr][ic + 0] = f2bf(v.x);
            tile[rr][ic + 1] = f2bf(v.y);
            tile[rr][ic + 2] = f2bf(v.z);
            tile[rr][ic + 3] = f2bf(v.w);
        }
        __syncthreads();
        const int n = t & 63, kc = (t >> 6) * 16;
        unsigned short* op = outp + (size_t)(c0 + n) * 256 + r0 + kc;
        unsigned int wo[8];
#pragma unroll
        for (int i = 0; i < 8; ++i)
            wo[i] = (unsigned int)tile[kc + 2 * i][n] | ((unsigned int)tile[kc + 2 * i + 1][n] << 16);
        *(uint4*)op       = make_uint4(wo[0], wo[1], wo[2], wo[3]);
        *(uint4*)(op + 8) = make_uint4(wo[4], wo[5], wo[6], wo[7]);
    }
}

// ---------------------------------------------------------------------------
// Final row instance-norm + leaky-relu, fp32 -> fp32. 1 block per 2048-row.
// ---------------------------------------------------------------------------
__global__ __launch_bounds__(256)
void row_norm_lrelu(const float* __restrict__ in, float* __restrict__ out)
{
    const size_t row = blockIdx.x;
    const float4* p = (const float4*)(in + row * 2048);
    float4* q = (float4*)(out + row * 2048);
    const int t = threadIdx.x;

    float4 v0 = p[t];
    float4 v1 = p[t + 256];

    float s  = v0.x + v0.y + v0.z + v0.w + v1.x + v1.y + v1.z + v1.w;
    float ss = v0.x * v0.x + v0.y * v0.y + v0.z * v0.z + v0.w * v0.w +
               v1.x * v1.x + v1.y * v1.y + v1.z * v1.z + v1.w * v1.w;
#pragma unroll
    for (int off = 32; off > 0; off >>= 1) {
        s  += __shfl_down(s, off, 64);
        ss += __shfl_down(ss, off, 64);
    }
    __shared__ float red[10];
    const int wid = t >> 6;
    if ((t & 63) == 0) { red[wid] = s; red[4 + wid] = ss; }
    __syncthreads();
    if (t == 0) {
        const float S  = red[0] + red[1] + red[2] + red[3];
        const float SS = red[4] + red[5] + red[6] + red[7];
        const float mu = S * (1.0f / 2048.0f);
        const float var = SS * (1.0f / 2048.0f) - mu * mu;
        red[8] = mu;
        red[9] = rsqrtf(var + EPS_IN);
    }
    __syncthreads();
    const float mu = red[8], rs = red[9];
#define NRM(x) { float e = ((x) - mu) * rs; (x) = (e >= 0.0f) ? e : LRELU_SLOPE * e; }
    NRM(v0.x) NRM(v0.y) NRM(v0.z) NRM(v0.w)
    NRM(v1.x) NRM(v1.y) NRM(v1.z) NRM(v1.w)
#undef NRM
    q[t] = v0;
    q[t + 256] = v1;
}

// ---------------------------------------------------------------------------
extern "C" void kernel_launch(void* const* d_in, const int* in_sizes, int n_in,
                              void* d_out, int out_size, void* d_ws, size_t ws_size,
                              hipStream_t stream)
{
    const float* feat = (const float*)d_in[0];
    const float* W1   = (const float*)d_in[1];
    const float* W2   = (const float*)d_in[2];
    const float* W3   = (const float*)d_in[3];
    const float* W4   = (const float*)d_in[4];
    float* out = (float*)d_out;

    char* w = (char*)d_ws;
    // Region A (0..50.3MB): ybf; after x4-GEMM consumes it (as D), reused for
    // x4Ts (33.5MB) + z (16.8MB). ybf stays live through the x4-GEMM: its
    // EP_SUB_T_SPLIT_NORM epilogue reads D rows 0..511 (x1) while writing
    // x4Ts into the SAME region -- but x4Ts[n][m] writes land at byte offsets
    // (n*1024+m)*2 which overlap ybf rows... NOT safe in-place. Keep x4Ts in
    // its own region instead (plenty of ws).
    unsigned short* ybf   = (unsigned short*)(w + 0);          // 50331648 B
    unsigned short* featT = (unsigned short*)(w + 50331648);   //  8388608 B
    unsigned short* x2T   = (unsigned short*)(w + 58720256);   // 16777216 B
    unsigned short* x4Ts  = (unsigned short*)(w + 75497472);   // 33554432 B
    unsigned short* Amb   = (unsigned short*)(w + 109051904);  //  4194304 B
    unsigned short* Wcatb = (unsigned short*)(w + 113246208);  //   786432 B
    unsigned short* W4cat = (unsigned short*)(w + 114032640);  //   524288 B
    float2*         part1 = (float2*)(w + 114556928);          //  1572864 B
    float2*         stats = (float2*)(w + 116129792);          //    98304 B
    float*          z     = (float*)(w + 116228096);           // 16777216 B

    // prep: weights cast + feat transpose (merged)
    prep<<<1536, 256, 0, stream>>>(W1, W2, W3, W4, Wcatb, W4cat, feat, featT);

    // GEMM1: ybf raw bf16 + stats partials. M=1536 N=2048 K=256.
    gemm_tn<128, 128, EP_BF16_STATS><<<dim3(16, 12, 8), 256, 0, stream>>>(
        Wcatb, featT, nullptr, ybf, nullptr, part1,
        256, 256, 256, 0, 2048, 0, 524288, 0, 3145728);

    reduce_stats<<<48, 256, 0, stream>>>(part1, stats);

    // x2T = normlrelu(x2)^T (only remaining materialized norm)
    transpose_norm_x2<<<dim3(32, 8, 8), 256, 0, stream>>>(ybf, stats, x2T);

    // Am = nl(x3) @ nl(x1)^T, norm fused into staging. 512 blocks.
    gemm_am<<<dim3(8, 8, 8), 256, 0, stream>>>(ybf, stats, Amb);

    // x4Ts = split(nl(x1) - Am@x2n)^T : M=512 N=2048 K=512; D = raw ybf x1
    // rows + stats (norm in epilogue). 512 blocks.
    gemm_tn<128, 128, EP_SUB_T_SPLIT_NORM><<<dim3(16, 4, 8), 256, 0, stream>>>(
        Amb, x2T, ybf, x4Ts, stats, nullptr,
        512, 512, 512, 2048, 1024, 262144, 1048576, 3145728, 2097152);

    // z = [W4|W4] @ x4Ts : M=256 N=2048 K=1024, fp32. 512 blocks.
    gemm_tn<128, 64, EP_F32><<<dim3(32, 2, 8), 256, 0, stream>>>(
        W4cat, x4Ts, nullptr, z, nullptr, nullptr,
        1024, 1024, 1024, 0, 2048, 0, 2097152, 0, 524288);

    // out = lrelu(inorm(z))
    row_norm_lrelu<<<2048, 256, 0, stream>>>(z, out);
}

// Round 10
// 208.901 us; speedup vs baseline: 1.0655x; 1.0655x over previous
//
#include <hip/hip_runtime.h>
#include <stdint.h>

// B=8, C=256, N=2048. Pipeline (reassociated: x3@(x1^T x2) == (x3@x1^T)@x2):
//   prep:  Wcatb=bf16([W1;W2;W3]), W4cat=bf16([W4|W4]), featT=bf16(feat^T)
//   ybf   = Wcat@feat RAW bf16 + row partials   [8,1536,2048]
//   stats = reduce(partials) -> (mu, rsqrt)     [12288]
//   normx: x2T = nl(x2)^T [8,2048,512]; x1n3 = nl(x1)|nl(x3) [8,1024,2048]
//   Amb   = x3n @ x1n^T (bf16)                  [8,512,512]
//   x4Ts  = split(nl(x1) - Am@x2n)^T (D=raw ybf+stats)  [8,2048,1024] hi|lo
//   z     = [W4|W4] @ x4Ts (fp32)               [8,256,2048]
//   out   = lrelu(inorm(z))
// Lessons: r5 coop 1-blk/CU = -60us (latency). r9 norm-fused-into-staging =
// -12us (8x redundant VALU norm; materialize-once wins when reuse>1).
// r10: all GEMMs use 1D grid with XCD batch-affinity swizzle (bid&7 = batch,
// T1): each batch's operands L2-resident on its XCD.

#define LRELU_SLOPE 0.2f
#define EPS_IN 1e-5f

typedef __attribute__((ext_vector_type(8))) short short8v;  // 8 bf16 (4 VGPR)
typedef __attribute__((ext_vector_type(4))) float f32x4;

__device__ __forceinline__ unsigned short f2bf(float f) {
    unsigned int u = __builtin_bit_cast(unsigned int, f);
    u = (u + 0x7fffu + ((u >> 16) & 1u)) >> 16;  // RNE
    return (unsigned short)u;
}
__device__ __forceinline__ float bf2f(unsigned short h) {
    return __builtin_bit_cast(float, (unsigned int)h << 16);
}

typedef const __attribute__((address_space(1))) unsigned int* as1_uint_ptr;
typedef __attribute__((address_space(3))) unsigned int* as3_uint_ptr;

#define GLL16(g, l) __builtin_amdgcn_global_load_lds( \
    (as1_uint_ptr)(const void*)(g), (as3_uint_ptr)(void*)(l), 16, 0, 0)

enum { EP_F32 = 0, EP_BF16 = 1, EP_SUB_T_SPLIT_NORM = 2, EP_BF16_STATS = 3 };

// ---------------------------------------------------------------------------
// TN bf16 MFMA GEMM, 2-phase double-buffered, XCD batch-affinity swizzle.
// A:[M][K], B:[N][K] k-major. BK=32, 4 waves (2x2).
// Launch: grid(ntx*nty*8); bz = bid&7 (XCD-pinned batch), tile = bid>>3.
// EP_F32: C fp32. EP_BF16: C bf16. EP_BF16_STATS: C bf16 + row partials.
// EP_SUB_T_SPLIT_NORM: dv = lrelu((bf2f(D)-mu)*rs); s = dv - acc;
//   C bf16 [N][ldc]: hi at [n][m], lo at [n][m+ldc/2].
// ---------------------------------------------------------------------------
template<int BM, int BN, int EP>
__global__ __launch_bounds__(256)
void gemm_tn(const unsigned short* __restrict__ A, const unsigned short* __restrict__ B,
             const unsigned short* __restrict__ Dm, void* __restrict__ Cv,
             const float2* __restrict__ stats, float2* __restrict__ part,
             int ntx,
             int K, int lda, int ldb, int ldd, int ldc,
             int64_t sA, int64_t sB, int64_t sD, int64_t sC)
{
    constexpr int FM = BM / 32, FN = BN / 32;
    const int bid = blockIdx.x;
    const int bz = bid & 7;          // XCD-affinity: batch pinned per XCD
    const int rt = bid >> 3;
    const int tx = rt % ntx, ty = rt / ntx;
    A += sA * bz;
    B += sB * bz;

    const int i0 = ty * BM;
    const int j0 = tx * BN;

    __shared__ __align__(16) unsigned short As[2][BM * 32];
    __shared__ __align__(16) unsigned short Bs[2][BN * 32];

    const int t = threadIdx.x;
    const int w = t >> 6, l = t & 63;
    const int wr = w >> 1, wc = w & 1;
    const int srow = l >> 2, skq = (l & 3) * 8;

    f32x4 acc[FM][FN];
#pragma unroll
    for (int fm = 0; fm < FM; ++fm)
#pragma unroll
        for (int fn = 0; fn < FN; ++fn)
            acc[fm][fn] = (f32x4){0.f, 0.f, 0.f, 0.f};

    const int NT = K / 32;

    // prologue: stage tile 0 into buffer 0
#pragma unroll
    for (int q = 0; q < BM / 64; ++q) {
        const int seg = w * (BM / 64) + q;
        GLL16(A + (size_t)(i0 + seg * 16 + srow) * lda + skq, &As[0][seg * 512]);
    }
#pragma unroll
    for (int q = 0; q < BN / 64; ++q) {
        const int seg = w * (BN / 64) + q;
        GLL16(B + (size_t)(j0 + seg * 16 + srow) * ldb + skq, &Bs[0][seg * 512]);
    }
    __syncthreads();  // drains vmcnt: tile 0 resident

    for (int tt = 0; tt < NT; ++tt) {
        const int cur = tt & 1;
        if (tt + 1 < NT) {  // stage next tile (flies during compute)
            const int k0 = (tt + 1) * 32;
#pragma unroll
            for (int q = 0; q < BM / 64; ++q) {
                const int seg = w * (BM / 64) + q;
                GLL16(A + (size_t)(i0 + seg * 16 + srow) * lda + k0 + skq, &As[cur ^ 1][seg * 512]);
            }
#pragma unroll
            for (int q = 0; q < BN / 64; ++q) {
                const int seg = w * (BN / 64) + q;
                GLL16(B + (size_t)(j0 + seg * 16 + srow) * ldb + k0 + skq, &Bs[cur ^ 1][seg * 512]);
            }
        }
        short8v a[FM], b[FN];
#pragma unroll
        for (int fm = 0; fm < FM; ++fm)
            a[fm] = *(const short8v*)&As[cur][(wr * (BM / 2) + fm * 16 + (l & 15)) * 32 + (l >> 4) * 8];
#pragma unroll
        for (int fn = 0; fn < FN; ++fn)
            b[fn] = *(const short8v*)&Bs[cur][(wc * (BN / 2) + fn * 16 + (l & 15)) * 32 + (l >> 4) * 8];
#pragma unroll
        for (int fm = 0; fm < FM; ++fm)
#pragma unroll
            for (int fn = 0; fn < FN; ++fn)
                acc[fm][fn] = __builtin_amdgcn_mfma_f32_16x16x32_bf16(a[fm], b[fn], acc[fm][fn], 0, 0, 0);
        __syncthreads();  // next-tile GLLs done + reads of cur done
    }

    // C/D frag: col = lane&15, row = (lane>>4)*4 + reg.
    const int cr4 = (l >> 4) * 4;
    const int cc = l & 15;

    if constexpr (EP == EP_F32) {
        float* C = (float*)Cv + sC * bz;
#pragma unroll
        for (int fm = 0; fm < FM; ++fm)
#pragma unroll
            for (int fn = 0; fn < FN; ++fn)
#pragma unroll
                for (int r = 0; r < 4; ++r)
                    C[(size_t)(i0 + wr * (BM / 2) + fm * 16 + cr4 + r) * ldc +
                      (j0 + wc * (BN / 2) + fn * 16 + cc)] = acc[fm][fn][r];
    } else if constexpr (EP == EP_BF16) {
        unsigned short* C = (unsigned short*)Cv + sC * bz;
#pragma unroll
        for (int fm = 0; fm < FM; ++fm)
#pragma unroll
            for (int fn = 0; fn < FN; ++fn)
#pragma unroll
                for (int r = 0; r < 4; ++r)
                    C[(size_t)(i0 + wr * (BM / 2) + fm * 16 + cr4 + r) * ldc +
                      (j0 + wc * (BN / 2) + fn * 16 + cc)] = f2bf(acc[fm][fn][r]);
    } else if constexpr (EP == EP_SUB_T_SPLIT_NORM) {
        const unsigned short* D = Dm + sD * bz;
        unsigned short* C = (unsigned short*)Cv + sC * bz;
#pragma unroll
        for (int fm = 0; fm < FM; ++fm) {
            const int grow0 = i0 + wr * (BM / 2) + fm * 16 + cr4;
            float2 st[4];
#pragma unroll
            for (int r = 0; r < 4; ++r) st[r] = stats[bz * 1536 + grow0 + r];
#pragma unroll
            for (int fn = 0; fn < FN; ++fn) {
                const int gcol = j0 + wc * (BN / 2) + fn * 16 + cc;
                ushort4 hi4, lo4;
#pragma unroll
                for (int r = 0; r < 4; ++r) {
                    float dv = (bf2f(D[(size_t)(grow0 + r) * ldd + gcol]) - st[r].x) * st[r].y;
                    dv = dv >= 0.f ? dv : LRELU_SLOPE * dv;
                    const float sv = dv - acc[fm][fn][r];
                    const unsigned short h = f2bf(sv);
                    ((unsigned short*)&hi4)[r] = h;
                    ((unsigned short*)&lo4)[r] = f2bf(sv - bf2f(h));
                }
                *(ushort4*)&C[(size_t)gcol * ldc + grow0] = hi4;
                *(ushort4*)&C[(size_t)gcol * ldc + (ldc >> 1) + grow0] = lo4;
            }
        }
    } else {  // EP_BF16_STATS
        unsigned short* C = (unsigned short*)Cv + sC * bz;
        __shared__ float2 wp[2][BM];
#pragma unroll
        for (int fm = 0; fm < FM; ++fm) {
#pragma unroll
            for (int r = 0; r < 4; ++r) {
                float s = 0.f, q = 0.f;
#pragma unroll
                for (int fn = 0; fn < FN; ++fn) {
                    const float v = acc[fm][fn][r];
                    s += v; q += v * v;
                    C[(size_t)(i0 + wr * (BM / 2) + fm * 16 + cr4 + r) * ldc +
                      (j0 + wc * (BN / 2) + fn * 16 + cc)] = f2bf(v);
                }
#pragma unroll
                for (int m = 1; m < 16; m <<= 1) {
                    s += __shfl_xor(s, m, 64);
                    q += __shfl_xor(q, m, 64);
                }
                if ((l & 15) == 0)
                    wp[wc][wr * (BM / 2) + fm * 16 + cr4 + r] = make_float2(s, q);
            }
        }
        __syncthreads();
        if (t < BM) {
            const float2 p0 = wp[0][t], p1 = wp[1][t];
            part[(size_t)(bz * 1536 + i0 + t) * ntx + tx] =
                make_float2(p0.x + p1.x, p0.y + p1.y);
        }
    }
}

// ---------------------------------------------------------------------------
// reduce partials -> (mu, rsqrt(var+eps)) per row. 12288 rows x 16 jtiles.
// ---------------------------------------------------------------------------
__global__ __launch_bounds__(256)
void reduce_stats(const float2* __restrict__ part, float2* __restrict__ stats)
{
    const int row = blockIdx.x * 256 + threadIdx.x;
    float S = 0.f, Q = 0.f;
#pragma unroll
    for (int j = 0; j < 16; ++j) {
        const float2 p = part[(size_t)row * 16 + j];
        S += p.x; Q += p.y;
    }
    const float mu = S * (1.0f / 2048.0f);
    const float var = Q * (1.0f / 2048.0f) - mu * mu;
    stats[row] = make_float2(mu, rsqrtf(var + EPS_IN));
}

// normalize + lrelu 8 bf16 packed in uint4 -> uint4
__device__ __forceinline__ uint4 norm8(uint4 v, float2 st)
{
    const unsigned int wd[4] = {v.x, v.y, v.z, v.w};
    unsigned int o[4];
#pragma unroll
    for (int i = 0; i < 4; ++i) {
        float a = __builtin_bit_cast(float, wd[i] << 16);
        float b = __builtin_bit_cast(float, wd[i] & 0xffff0000u);
        a = (a - st.x) * st.y; a = a >= 0.f ? a : LRELU_SLOPE * a;
        b = (b - st.x) * st.y; b = b >= 0.f ? b : LRELU_SLOPE * b;
        o[i] = (unsigned int)f2bf(a) | ((unsigned int)f2bf(b) << 16);
    }
    return make_uint4(o[0], o[1], o[2], o[3]);
}

// ---------------------------------------------------------------------------
// Merged: blocks [0,2048) = x2T = normlrelu(x2)^T; blocks [2048,10240) =
// x1n3 rows (x1n | x3n). 256 threads. Branch is block-uniform. (r8 proven)
// ---------------------------------------------------------------------------
__global__ __launch_bounds__(256)
void normx(const unsigned short* __restrict__ ybf, const float2* __restrict__ stats,
           unsigned short* __restrict__ x2T, unsigned short* __restrict__ x1n3)
{
    const int b = blockIdx.x;
    const int t = threadIdx.x;
    if (b < 2048) {
        __shared__ __align__(16) unsigned short tile[64][68];
        const int bx = b & 31, by = (b >> 5) & 7, bz = b >> 8;
        const unsigned short* in = ybf + (size_t)bz * 3145728 + (size_t)512 * 2048;
        unsigned short* outp = x2T + (size_t)bz * 1048576;
        const int r0 = by * 64, c0 = bx * 64;
        const int ir = t >> 4, ic = (t & 15) * 4;
#pragma unroll
        for (int q = 0; q < 4; ++q) {
            const int rr = q * 16 + ir;
            const float2 st = stats[bz * 1536 + 512 + r0 + rr];
            const ushort4 v = *(const ushort4*)&in[(size_t)(r0 + rr) * 2048 + c0 + ic];
            const unsigned short vv[4] = {v.x, v.y, v.z, v.w};
#pragma unroll
            for (int j = 0; j < 4; ++j) {
                float e = (bf2f(vv[j]) - st.x) * st.y;
                e = e >= 0.f ? e : LRELU_SLOPE * e;
                tile[rr][ic + j] = f2bf(e);
            }
        }
        __syncthreads();
        const int n = t & 63, kc = (t >> 6) * 16;
        unsigned short* op = outp + (size_t)(c0 + n) * 512 + r0 + kc;
        unsigned int wo[8];
#pragma unroll
        for (int i = 0; i < 8; ++i)
            wo[i] = (unsigned int)tile[kc + 2 * i][n] | ((unsigned int)tile[kc + 2 * i + 1][n] << 16);
        *(uint4*)op       = make_uint4(wo[0], wo[1], wo[2], wo[3]);
        *(uint4*)(op + 8) = make_uint4(wo[4], wo[5], wo[6], wo[7]);
    } else {
        const int r = b - 2048;
        const int x = r & 1023, bz = r >> 10;
        const int src = (x < 512) ? x : (x + 512);  // x1 rows or x3 rows
        const float2 st = stats[bz * 1536 + src];
        const uint4 v = ((const uint4*)(ybf + (size_t)bz * 3145728 + (size_t)src * 2048))[t];
        ((uint4*)(x1n3 + (size_t)bz * 2097152 + (size_t)x * 2048))[t] = norm8(v, st);
    }
}

// ---------------------------------------------------------------------------
// Merged prep: blocks [0,512) cast weights; blocks [512,1536) feat^T->bf16.
// ---------------------------------------------------------------------------
__global__ __launch_bounds__(256)
void prep(const float* __restrict__ W1, const float* __restrict__ W2,
          const float* __restrict__ W3, const float* __restrict__ W4,
          unsigned short* __restrict__ Wcatb, unsigned short* __restrict__ W4cat,
          const float* __restrict__ feat, unsigned short* __restrict__ featT)
{
    const int b = blockIdx.x;
    const int t = threadIdx.x;
    if (b < 512) {
        const int wsel = b >> 7;
        const int local = ((b & 127) * 256 + t) * 4;
        const float* src = (wsel == 0) ? W1 : (wsel == 1) ? W2 : (wsel == 2) ? W3 : W4;
        const float4 v = *(const float4*)(src + local);
        const ushort4 pk = make_ushort4(f2bf(v.x), f2bf(v.y), f2bf(v.z), f2bf(v.w));
        if (wsel < 3) {
            *(ushort4*)(Wcatb + (size_t)wsel * 131072 + local) = pk;
        } else {
            const int o = local >> 9, c = local & 511;
            *(ushort4*)(W4cat + (size_t)o * 1024 + c)       = pk;
            *(ushort4*)(W4cat + (size_t)o * 1024 + 512 + c) = pk;
        }
    } else {
        __shared__ __align__(16) unsigned short tile[64][68];
        const int r = b - 512;
        const int bx = r & 31, by = (r >> 5) & 3, bz = r >> 7;
        const float* ip0 = feat + (size_t)bz * 524288;
        unsigned short* outp = featT + (size_t)bz * 524288;
        const int r0 = by * 64, c0 = bx * 64;
        const int ir = t >> 4, ic = (t & 15) * 4;
#pragma unroll
        for (int q = 0; q < 4; ++q) {
            const int rr = q * 16 + ir;
            const float4 v = *(const float4*)&ip0[(size_t)(r0 + rr) * 2048 + c0 + ic];
            tile[rr][ic + 0] = f2bf(v.x);
            tile[rr][ic + 1] = f2bf(v.y);
            tile[rr][ic + 2] = f2bf(v.z);
            tile[rr][ic + 3] = f2bf(v.w);
        }
        __syncthreads();
        const int n = t & 63, kc = (t >> 6) * 16;
        unsigned short* op = outp + (size_t)(c0 + n) * 256 + r0 + kc;
        unsigned int wo[8];
#pragma unroll
        for (int i = 0; i < 8; ++i)
            wo[i] = (unsigned int)tile[kc + 2 * i][n] | ((unsigned int)tile[kc + 2 * i + 1][n] << 16);
        *(uint4*)op       = make_uint4(wo[0], wo[1], wo[2], wo[3]);
        *(uint4*)(op + 8) = make_uint4(wo[4], wo[5], wo[6], wo[7]);
    }
}

// ---------------------------------------------------------------------------
// Final row instance-norm + leaky-relu, fp32 -> fp32. 1 block per 2048-row.
// ---------------------------------------------------------------------------
__global__ __launch_bounds__(256)
void row_norm_lrelu(const float* __restrict__ in, float* __restrict__ out)
{
    const size_t row = blockIdx.x;
    const float4* p = (const float4*)(in + row * 2048);
    float4* q = (float4*)(out + row * 2048);
    const int t = threadIdx.x;

    float4 v0 = p[t];
    float4 v1 = p[t + 256];

    float s  = v0.x + v0.y + v0.z + v0.w + v1.x + v1.y + v1.z + v1.w;
    float ss = v0.x * v0.x + v0.y * v0.y + v0.z * v0.z + v0.w * v0.w +
               v1.x * v1.x + v1.y * v1.y + v1.z * v1.z + v1.w * v1.w;
#pragma unroll
    for (int off = 32; off > 0; off >>= 1) {
        s  += __shfl_down(s, off, 64);
        ss += __shfl_down(ss, off, 64);
    }
    __shared__ float red[10];
    const int wid = t >> 6;
    if ((t & 63) == 0) { red[wid] = s; red[4 + wid] = ss; }
    __syncthreads();
    if (t == 0) {
        const float S  = red[0] + red[1] + red[2] + red[3];
        const float SS = red[4] + red[5] + red[6] + red[7];
        const float mu = S * (1.0f / 2048.0f);
        const float var = SS * (1.0f / 2048.0f) - mu * mu;
        red[8] = mu;
        red[9] = rsqrtf(var + EPS_IN);
    }
    __syncthreads();
    const float mu = red[8], rs = red[9];
#define NRM(x) { float e = ((x) - mu) * rs; (x) = (e >= 0.0f) ? e : LRELU_SLOPE * e; }
    NRM(v0.x) NRM(v0.y) NRM(v0.z) NRM(v0.w)
    NRM(v1.x) NRM(v1.y) NRM(v1.z) NRM(v1.w)
#undef NRM
    q[t] = v0;
    q[t + 256] = v1;
}

// ---------------------------------------------------------------------------
extern "C" void kernel_launch(void* const* d_in, const int* in_sizes, int n_in,
                              void* d_out, int out_size, void* d_ws, size_t ws_size,
                              hipStream_t stream)
{
    const float* feat = (const float*)d_in[0];
    const float* W1   = (const float*)d_in[1];
    const float* W2   = (const float*)d_in[2];
    const float* W3   = (const float*)d_in[3];
    const float* W4   = (const float*)d_in[4];
    float* out = (float*)d_out;

    char* w = (char*)d_ws;
    // Aliasing: ybf dead after x4-GEMM (D-read) -> z reuses ybf region.
    //           x1n3 dead after Am-GEMM -> x4Ts reuses x1n3 region.
    unsigned short* ybf   = (unsigned short*)(w + 0);          // 50331648 B
    float*          z     = (float*)(w + 0);                   // 16777216 B (alias ybf)
    unsigned short* featT = (unsigned short*)(w + 50331648);   //  8388608 B
    unsigned short* x2T   = (unsigned short*)(w + 58720256);   // 16777216 B
    unsigned short* x1n3  = (unsigned short*)(w + 75497472);   // 33554432 B
    unsigned short* x4Ts  = (unsigned short*)(w + 75497472);   // 33554432 B (alias x1n3)
    unsigned short* Amb   = (unsigned short*)(w + 109051904);  //  4194304 B
    unsigned short* Wcatb = (unsigned short*)(w + 113246208);  //   786432 B
    unsigned short* W4cat = (unsigned short*)(w + 114032640);  //   524288 B
    float2*         part1 = (float2*)(w + 114556928);          //  1572864 B
    float2*         stats = (float2*)(w + 116129792);          //    98304 B

    // prep: weights cast + feat transpose (merged)
    prep<<<1536, 256, 0, stream>>>(W1, W2, W3, W4, Wcatb, W4cat, feat, featT);

    // GEMM1: ybf raw bf16 + stats partials. M=1536 N=2048 K=256. ntx=16 nty=12.
    gemm_tn<128, 128, EP_BF16_STATS><<<1536, 256, 0, stream>>>(
        Wcatb, featT, nullptr, ybf, nullptr, part1, 16,
        256, 256, 256, 0, 2048, 0, 524288, 0, 3145728);

    reduce_stats<<<48, 256, 0, stream>>>(part1, stats);

    // x2T + x1n3 (merged, r8-proven)
    normx<<<10240, 256, 0, stream>>>(ybf, stats, x2T, x1n3);

    // Am = x3n @ x1n^T : M=512 N=512 K=2048. ntx=8 nty=8 -> 512 blocks.
    gemm_tn<64, 64, EP_BF16><<<512, 256, 0, stream>>>(
        x1n3 + 1048576 /*x3n*/, x1n3 /*x1n*/, nullptr, Amb, nullptr, nullptr, 8,
        2048, 2048, 2048, 0, 512, 2097152, 2097152, 0, 262144);

    // x4Ts = split(nl(x1) - Am@x2n)^T : M=512 N=2048 K=512; D = raw ybf x1
    // rows + stats. ntx=16 nty=4 -> 512 blocks. Writes over dead x1n3.
    gemm_tn<128, 128, EP_SUB_T_SPLIT_NORM><<<512, 256, 0, stream>>>(
        Amb, x2T, ybf, x4Ts, stats, nullptr, 16,
        512, 512, 512, 2048, 1024, 262144, 1048576, 3145728, 2097152);

    // z = [W4|W4] @ x4Ts : M=256 N=2048 K=1024, fp32. ntx=32 nty=2 -> 512
    // blocks. Writes over dead ybf.
    gemm_tn<128, 64, EP_F32><<<512, 256, 0, stream>>>(
        W4cat, x4Ts, nullptr, z, nullptr, nullptr, 32,
        1024, 1024, 1024, 0, 2048, 0, 2097152, 0, 524288);

    // out = lrelu(inorm(z))
    row_norm_lrelu<<<2048, 256, 0, stream>>>(z, out);
}